// Round 7
// baseline (435.287 us; speedup 1.0000x reference)
//
#include <hip/hip_runtime.h>

// Problem constants
#define BB 4
#define TT 2048
#define LL 2048
#define DM 512     // d_model
#define AD 512     // attn dim
#define NH 8       // heads
#define HD 64      // head dim
// 1/sqrt(512) * log2(e): Q folded scale so softmax runs in exp2 domain
#define Q_SCALE 0.06375871295f

typedef __bf16 bf16;
typedef __attribute__((ext_vector_type(8))) __bf16 bf16x8;
typedef __attribute__((ext_vector_type(4))) __bf16 bf16x4;
typedef __attribute__((ext_vector_type(4))) float  f32x4;

__device__ __forceinline__ f32x4 mfma16(bf16x8 a, bf16x8 b, f32x4 c) {
  return __builtin_amdgcn_mfma_f32_16x16x32_bf16(a, b, c, 0, 0, 0);
}

__device__ __forceinline__ float fexp2(float x) {
#if __has_builtin(__builtin_amdgcn_exp2f)
  return __builtin_amdgcn_exp2f(x);
#else
  return exp2f(x);
#endif
}

// ---------------------------------------------------------------- RoPE cos/sin table
__global__ void k_tab(const float* __restrict__ xm, const float* __restrict__ cm,
                      float2* __restrict__ tab) {
  int which = blockIdx.z, b = blockIdx.y, t0 = blockIdx.x * 128;
  const float* mp = (which ? cm : xm) + b * 2048;
  float s = 0.f;
  for (int i = threadIdx.x; i < 2048; i += 256) s += mp[i];
  #pragma unroll
  for (int o = 32; o > 0; o >>= 1) s += __shfl_down(s, o, 64);
  __shared__ float red[4];
  if ((threadIdx.x & 63) == 0) red[threadIdx.x >> 6] = s;
  __syncthreads();
  float len = red[0] + red[1] + red[2] + red[3];
  float2* tb = tab + ((size_t)(which * 4 + b) * 2048) * 32;
  for (int e = threadIdx.x; e < 128 * 32; e += 256) {
    int tl = e >> 5, i = e & 31;
    float theta = 10.f * __expf(-(float)i * 0.28782313662425576f);
    float f = ((float)(t0 + tl) / len) * theta;
    float sn, cs;
    __sincosf(f, &sn, &cs);
    tb[(size_t)(t0 + tl) * 32 + i] = make_float2(cs, sn);
  }
}

// ---------------------------------------------------------------- 4 weights f32 -> bf16 (one launch)
__global__ void k_cvt_w(const float* __restrict__ w0, const float* __restrict__ w1,
                        const float* __restrict__ w2, const float* __restrict__ w3,
                        bf16* __restrict__ dst) {
  int widx = blockIdx.x >> 6;
  const float* src = (widx == 0) ? w0 : (widx == 1) ? w1 : (widx == 2) ? w2 : w3;
  bf16* d = dst + (size_t)widx * 262144;
  for (int i = (blockIdx.x & 63) * 256 + threadIdx.x; i < 65536; i += 16384) {
    float4 v = ((const float4*)src)[i];
    bf16x4 o;
    o.x = (bf16)v.x; o.y = (bf16)v.y; o.z = (bf16)v.z; o.w = (bf16)v.w;
    ((bf16x4*)d)[i] = o;
  }
}

// ---------------------------------------------------------------- f32 -> bf16 convert (vec4)
__global__ void k_cvt(const float* __restrict__ src, bf16* __restrict__ dst, int n4) {
  int i = blockIdx.x * blockDim.x + threadIdx.x;
  int stride = gridDim.x * blockDim.x;
  for (; i < n4; i += stride) {
    float4 v = ((const float4*)src)[i];
    bf16x4 o;
    o.x = (bf16)v.x; o.y = (bf16)v.y; o.z = (bf16)v.z; o.w = (bf16)v.w;
    ((bf16x4*)dst)[i] = o;
  }
}

// ---------------------------------------------------------------- x (B,DM,T) f32 -> xb (B,T,DM) bf16
__global__ void k_tr_x(const float* __restrict__ x, bf16* __restrict__ xb) {
  __shared__ float tile[64][65];
  int t0 = blockIdx.x * 64, m0 = blockIdx.y * 64, b = blockIdx.z;
  int c = threadIdx.x & 63, rg = threadIdx.x >> 6;
  #pragma unroll
  for (int i = 0; i < 16; i++) {
    int r = rg * 16 + i;
    tile[r][c] = x[((size_t)b * DM + (m0 + r)) * TT + t0 + c];
  }
  __syncthreads();
  #pragma unroll
  for (int i = 0; i < 16; i++) {
    int r = rg * 16 + i;
    xb[((size_t)b * TT + (t0 + r)) * DM + m0 + c] = (bf16)tile[c][r];
  }
}

// ---------------------------------------------------------------- V (B,L,AD) bf16 -> Vf fragment-order
// Vf[b][h][ltile][frag f=nf*2+ks][lane][j]: lane(lg,lr), elem j = V[l0+lg*8+ks*32+j][d=nf*16+lr].
// Every k_attn V-fragment load becomes a contiguous 1KB wave burst (R5 fix: the old
// Vt layout made each frag load touch 16 cache lines -> TA request-rate bound).
__global__ void k_tr_vf(const bf16* __restrict__ Vb, bf16* __restrict__ Vf) {
  __shared__ bf16 vtile[64][72];   // [l][d], padded
  int l0b = blockIdx.x, h = blockIdx.y, b = blockIdx.z;
  int t = threadIdx.x;
  int l = t >> 2, c = t & 3;       // 4 x 32B chunks per 128B row
  const bf16* src = Vb + ((size_t)(b * 2048 + l0b * 64 + l)) * 512 + h * 64 + c * 16;
  *(bf16x8*)&vtile[l][c * 16]     = *(const bf16x8*)(src);
  *(bf16x8*)&vtile[l][c * 16 + 8] = *(const bf16x8*)(src + 8);
  __syncthreads();
  bf16* dst = Vf + ((size_t)((b * NH + h) * 32 + l0b)) * 4096;
  #pragma unroll
  for (int i = 0; i < 2; i++) {
    int o = (i * 256 + t) * 8;
    int f = o >> 9, lid = (o & 511) >> 3;
    int nf = f >> 1, ks = f & 1, lg = lid >> 4, lr = lid & 15;
    bf16x8 v8;
    #pragma unroll
    for (int j = 0; j < 8; j++) v8[j] = vtile[lg * 8 + ks * 32 + j][nf * 16 + lr];
    *(bf16x8*)(dst + o) = v8;
  }
}

// ---------------------------------------------------------------- K (B,L,AD) bf16 -> Kf fragment-order
// Kf[b][h][ltile][frag f=lf*2+ks][lane][j]: lane(lg,lr), elem j = K[l0+lf*16+lr][k=lg*8+ks*32+j].
// j is contiguous in k -> 16B gather reads, 16B coalesced writes. One-shot 8MB pass.
__global__ void k_repack_k(const bf16* __restrict__ Kb, bf16* __restrict__ Kf) {
  int l0b = blockIdx.x, h = blockIdx.y, b = blockIdx.z;
  int t = threadIdx.x;
  bf16* dst = Kf + ((size_t)((b * NH + h) * 32 + l0b)) * 4096;
  #pragma unroll
  for (int i = 0; i < 2; i++) {
    int o = (i * 256 + t) * 8;
    int f = o >> 9, lid = (o & 511) >> 3;
    int lf = f >> 1, ks = f & 1, lg = lid >> 4, lr = lid & 15;
    const bf16* src = Kb + ((size_t)(b * 2048 + l0b * 64 + lf * 16 + lr)) * 512
                         + h * 64 + lg * 8 + ks * 32;
    *(bf16x8*)(dst + o) = *(const bf16x8*)(src);
  }
}

// ---------------------------------------------------------------- fused QKV projection GEMM + RoPE epilogue
#define QKV_BODY(K0, AC, BC, AN, BN)                                              \
  {                                                                               \
    int _kn = ((K0) + 32) & 511;                                                  \
    _Pragma("unroll")                                                             \
    for (int mf = 0; mf < 4; mf++) AN[mf] = *(const bf16x8*)(Arow + (size_t)mf * 16 * 512 + _kn); \
    _Pragma("unroll")                                                             \
    for (int nf = 0; nf < 4; nf++) BN[nf] = *(const bf16x8*)(Brow + (size_t)nf * 16 * 512 + _kn); \
    __builtin_amdgcn_sched_barrier(0);                                            \
    _Pragma("unroll")                                                             \
    for (int mf = 0; mf < 4; mf++)                                                \
      _Pragma("unroll")                                                           \
      for (int nf = 0; nf < 4; nf++)                                              \
        acc[mf][nf] = mfma16(AC[mf], BC[nf], acc[mf][nf]);                        \
  }

__global__ __launch_bounds__(256, 3) void k_qkv(
    const bf16* __restrict__ xb, const bf16* __restrict__ ctxb,
    const bf16* __restrict__ Wqb, const bf16* __restrict__ Wkb, const bf16* __restrict__ Wvb,
    const float* __restrict__ bq, const float* __restrict__ bk, const float* __restrict__ bv,
    const float2* __restrict__ tab,
    bf16* __restrict__ Qb, bf16* __restrict__ Kb, bf16* __restrict__ Vb) {
  int proj = blockIdx.z;
  const bf16* A     = (proj == 0) ? xb : ctxb;
  const bf16* Wt    = (proj == 0) ? Wqb : (proj == 1 ? Wkb : Wvb);
  const float* bias = (proj == 0) ? bq : (proj == 1 ? bk : bv);
  bf16* out         = (proj == 0) ? Qb : (proj == 1 ? Kb : Vb);

  int m0 = blockIdx.y * 128, n0 = blockIdx.x * 128;
  int wid = threadIdx.x >> 6, lane = threadIdx.x & 63;
  int lr = lane & 15, lg = lane >> 4;
  int mw = m0 + (wid >> 1) * 64, nw = n0 + (wid & 1) * 64;

  const bf16* Arow = A  + ((size_t)(mw + lr)) * 512 + lg * 8;
  const bf16* Brow = Wt + ((size_t)(nw + lr)) * 512 + lg * 8;

  f32x4 acc[4][4] = {};
  bf16x8 afA[4], afB[4], bvA[4], bvB[4];
  #pragma unroll
  for (int mf = 0; mf < 4; mf++) afA[mf] = *(const bf16x8*)(Arow + (size_t)mf * 16 * 512);
  #pragma unroll
  for (int nf = 0; nf < 4; nf++) bvA[nf] = *(const bf16x8*)(Brow + (size_t)nf * 16 * 512);

  for (int k0 = 0; k0 < 512; k0 += 64) {
    QKV_BODY(k0,      afA, bvA, afB, bvB)
    QKV_BODY(k0 + 32, afB, bvB, afA, bvA)
  }

  if (proj < 2) {
    float qs = (proj == 0) ? Q_SCALE : 1.0f;
    const float2* tb = tab + (size_t)proj * 4 * 2048 * 32;
    #pragma unroll
    for (int mf = 0; mf < 4; mf++)
      #pragma unroll
      for (int r = 0; r < 4; r++) {
        int row = mw + mf * 16 + lg * 4 + r;
        int b = row >> 11, t = row & 2047;
        const float2* trow = tb + ((size_t)b * 2048 + t) * 32;
        #pragma unroll
        for (int nf = 0; nf < 2; nf++) {
          int i = nf * 16 + lr;
          float2 cs = trow[i];
          float x1 = acc[mf][nf][r]     + bias[nw + nf * 16 + lr];
          float x2 = acc[mf][nf + 2][r] + bias[nw + (nf + 2) * 16 + lr];
          out[(size_t)row * 512 + nw + nf * 16 + lr]       = (bf16)((x1 * cs.x - x2 * cs.y) * qs);
          out[(size_t)row * 512 + nw + (nf + 2) * 16 + lr] = (bf16)((x1 * cs.y + x2 * cs.x) * qs);
        }
      }
  } else {
    #pragma unroll
    for (int nf = 0; nf < 4; nf++) {
      float bb = bias[nw + nf * 16 + lr];
      #pragma unroll
      for (int mf = 0; mf < 4; mf++)
        #pragma unroll
        for (int r = 0; r < 4; r++) {
          int row = mw + mf * 16 + lg * 4 + r;
          out[(size_t)row * 512 + nw + nf * 16 + lr] = (bf16)(acc[mf][nf][r] + bb);
        }
    }
  }
}

// ---------------------------------------------------------------- flash attention, fragment-order K/V
// R3/R5: 127us, all pipes idle -> diagnosed as TA line-request bound (each frag load
// touched 16 cache lines). Now every K/V fragment load is a contiguous 1KB burst from
// Kf/Vf. Keeps R4's K ping-pong prefetch (1 tile ahead) + early V issue + MODE ablation.
template<int MODE, int REP>
__global__ __launch_bounds__(256, 2) void k_attn_t(
    const bf16* __restrict__ Qb, const bf16* __restrict__ Kf, const bf16* __restrict__ Vf,
    bf16* __restrict__ AO) {
  int bid = blockIdx.x;
  int sw = (bid & 7) * 64 + (bid >> 3);   // bijective XCD swizzle (512 = 8*64)
  int qt = sw & 15, h = (sw >> 4) & 7, b = sw >> 7;

  int wid = threadIdx.x >> 6, lane = threadIdx.x & 63;
  int lr = lane & 15, lg = lane >> 4;
  int t0 = qt * 128 + wid * 32;

  __shared__ bf16 Plds[4][32 * 64];
  bf16* myP = &Plds[wid][0];

  // Q fragments (B-operand of swapped QK^T): elem (t = t0+tf*16+lr, k = lg*8+ks*32+j)
  const bf16* Qbase = Qb + ((size_t)(b * 2048 + t0 + lr)) * AD + h * HD + lg * 8;
  bf16x8 qf[2][2];
  #pragma unroll
  for (int tf = 0; tf < 2; tf++)
    #pragma unroll
    for (int ks = 0; ks < 2; ks++)
      qf[tf][ks] = *(const bf16x8*)(Qbase + (size_t)tf * 16 * AD + ks * 32);

  bf16x8 ones8;
  #pragma unroll
  for (int j = 0; j < 8; j++) ones8[j] = (bf16)1.0f;

  float mrow[2] = {-1e30f, -1e30f};
  f32x4 oacc[2][4] = {};
  f32x4 oext[2] = {};
  float dummy = 0.f;

  const bf16* KfB = Kf + ((size_t)((b * NH + h) * 32)) * 4096;
  const bf16* VfB = Vf + ((size_t)((b * NH + h) * 32)) * 4096;

  // prologue: K frags for tile 0
  bf16x8 kfA[4][2], kfB_[4][2], vf[4][2];
  #pragma unroll
  for (int lf = 0; lf < 4; lf++)
    #pragma unroll
    for (int ks = 0; ks < 2; ks++)
      kfA[lf][ks] = *(const bf16x8*)(KfB + (lf * 2 + ks) * 512 + lane * 8);

#define ATT_BODY(TCUR, KC, KN)                                                    \
  {                                                                               \
    const bf16* VfT = VfB + (size_t)(TCUR) * 4096;                                \
    const bf16* KfN = KfB + (size_t)(((TCUR) + 1) & 31) * 4096;                   \
    _Pragma("unroll")                                                             \
    for (int nf = 0; nf < 4; nf++)                                                \
      _Pragma("unroll")                                                           \
      for (int ks = 0; ks < 2; ks++)                                              \
        vf[nf][ks] = *(const bf16x8*)(VfT + (nf * 2 + ks) * 512 + lane * 8);      \
    _Pragma("unroll")                                                             \
    for (int lf = 0; lf < 4; lf++)                                                \
      _Pragma("unroll")                                                           \
      for (int ks = 0; ks < 2; ks++)                                              \
        KN[lf][ks] = *(const bf16x8*)(KfN + (lf * 2 + ks) * 512 + lane * 8);      \
    __builtin_amdgcn_sched_barrier(0);                                            \
    f32x4 sacc[4][2] = {};                                                        \
    __builtin_amdgcn_s_setprio(1);                                                \
    _Pragma("unroll")                                                             \
    for (int lf = 0; lf < 4; lf++)                                                \
      _Pragma("unroll")                                                           \
      for (int tf = 0; tf < 2; tf++)                                              \
        _Pragma("unroll")                                                         \
        for (int ks = 0; ks < 2; ks++)                                            \
          sacc[lf][tf] = mfma16(KC[lf][ks], qf[tf][ks], sacc[lf][tf]);            \
    __builtin_amdgcn_s_setprio(0);                                                \
    if constexpr (MODE == 0) {                                                    \
      _Pragma("unroll")                                                           \
      for (int lf = 0; lf < 4; lf++)                                              \
        _Pragma("unroll")                                                         \
        for (int tf = 0; tf < 2; tf++)                                            \
          dummy += sacc[lf][tf][0] + sacc[lf][tf][3];                             \
      _Pragma("unroll")                                                           \
      for (int nf = 0; nf < 4; nf++)                                              \
        dummy += (float)vf[nf][0][0] + (float)vf[nf][1][7];                       \
      dummy += (float)KN[0][0][0] + (float)KN[3][1][7];                           \
    } else {                                                                      \
      float mx[2];                                                                \
      _Pragma("unroll")                                                           \
      for (int tf = 0; tf < 2; tf++) {                                            \
        float mm = fmaxf(                                                         \
            fmaxf(fmaxf(fmaxf(sacc[0][tf][0], sacc[0][tf][1]), fmaxf(sacc[0][tf][2], sacc[0][tf][3])), \
                  fmaxf(fmaxf(sacc[1][tf][0], sacc[1][tf][1]), fmaxf(sacc[1][tf][2], sacc[1][tf][3]))), \
            fmaxf(fmaxf(fmaxf(sacc[2][tf][0], sacc[2][tf][1]), fmaxf(sacc[2][tf][2], sacc[2][tf][3])), \
                  fmaxf(fmaxf(sacc[3][tf][0], sacc[3][tf][1]), fmaxf(sacc[3][tf][2], sacc[3][tf][3])))); \
        mm = fmaxf(mm, __shfl_xor(mm, 16, 64));                                   \
        mm = fmaxf(mm, __shfl_xor(mm, 32, 64));                                   \
        mx[tf] = mm;                                                              \
      }                                                                           \
      int need = (mx[0] > mrow[0] + 8.f) | (mx[1] > mrow[1] + 8.f);               \
      if (__any(need)) {                                                          \
        float mn0 = fmaxf(mrow[0], mx[0]), mn1 = fmaxf(mrow[1], mx[1]);           \
        float co[2] = {fexp2(mrow[0] - mn0), fexp2(mrow[1] - mn1)};               \
        mrow[0] = mn0; mrow[1] = mn1;                                             \
        _Pragma("unroll")                                                         \
        for (int mf = 0; mf < 2; mf++)                                            \
          _Pragma("unroll")                                                       \
          for (int r = 0; r < 4; r++) {                                           \
            float cc = __shfl(co[mf], lg * 4 + r, 16);                            \
            oext[mf][r] *= cc;                                                    \
            _Pragma("unroll")                                                     \
            for (int nf = 0; nf < 4; nf++) oacc[mf][nf][r] *= cc;                 \
          }                                                                       \
      }                                                                           \
      _Pragma("unroll")                                                           \
      for (int tf = 0; tf < 2; tf++)                                              \
        _Pragma("unroll")                                                         \
        for (int lf = 0; lf < 4; lf++) {                                          \
          bf16x4 p4;                                                              \
          _Pragma("unroll")                                                       \
          for (int r = 0; r < 4; r++)                                             \
            p4[r] = (bf16)fexp2(sacc[lf][tf][r] - mrow[tf]);                      \
          int byte = (tf * 16 + lr) * 128 + (lf * 16 + lg * 4) * 2;               \
          byte ^= (lr & 7) << 4;                                                  \
          *(bf16x4*)((char*)myP + byte) = p4;                                     \
        }                                                                         \
      if constexpr (MODE == 1) {                                                  \
        dummy += (float)myP[lane];                                                \
        _Pragma("unroll")                                                         \
        for (int nf = 0; nf < 4; nf++) dummy += (float)vf[nf][0][0];              \
      } else {                                                                    \
        bf16x8 pa[2][2];                                                          \
        _Pragma("unroll")                                                         \
        for (int mf = 0; mf < 2; mf++)                                            \
          _Pragma("unroll")                                                       \
          for (int ks = 0; ks < 2; ks++) {                                        \
            int byte = (mf * 16 + lr) * 128 + (lg * 8 + ks * 32) * 2;             \
            byte ^= (lr & 7) << 4;                                                \
            pa[mf][ks] = *(const bf16x8*)((const char*)myP + byte);               \
          }                                                                       \
        __builtin_amdgcn_s_setprio(1);                                            \
        _Pragma("unroll")                                                         \
        for (int mf = 0; mf < 2; mf++) {                                          \
          _Pragma("unroll")                                                       \
          for (int nf = 0; nf < 4; nf++)                                          \
            _Pragma("unroll")                                                     \
            for (int ks = 0; ks < 2; ks++)                                        \
              oacc[mf][nf] = mfma16(pa[mf][ks], vf[nf][ks], oacc[mf][nf]);        \
          _Pragma("unroll")                                                       \
          for (int ks = 0; ks < 2; ks++)                                          \
            oext[mf] = mfma16(pa[mf][ks], ones8, oext[mf]);                       \
        }                                                                         \
        __builtin_amdgcn_s_setprio(0);                                            \
      }                                                                           \
    }                                                                             \
  }

  #pragma unroll 1
  for (int it = 0; it < 16 * REP; it++) {
    int t2 = (it * 2) & 31;
    ATT_BODY(t2,     kfA,  kfB_)
    ATT_BODY(t2 + 1, kfB_, kfA)
  }
#undef ATT_BODY

  if constexpr (MODE == 2) {
    // normalize, store AO (B,T,AD) bf16
    #pragma unroll
    for (int mf = 0; mf < 2; mf++)
      #pragma unroll
      for (int r = 0; r < 4; r++) {
        float inv = 1.0f / fmaxf(oext[mf][r], 1e-35f);
        int t = t0 + mf * 16 + lg * 4 + r;
        #pragma unroll
        for (int nf = 0; nf < 4; nf++)
          AO[((size_t)b * 2048 + t) * AD + h * HD + nf * 16 + lr] =
              (bf16)(oacc[mf][nf][r] * inv);
      }
  } else {
    // keepalive store (overwritten by the production dispatch)
    AO[((size_t)b * 2048 + t0 + lr) * AD + h * HD + lg] =
        (bf16)(dummy + mrow[0] + mrow[1] + oext[0][0] + oacc[0][0][0]);
  }
}

// ---------------------------------------------------------------- output projection, transposed store
#define OUT_BODY(K0, AC, BC, AN, BN)                                              \
  {                                                                               \
    int _kn = ((K0) + 32) & 511;                                                  \
    _Pragma("unroll")                                                             \
    for (int mf = 0; mf < 2; mf++) AN[mf] = *(const bf16x8*)(Abase + (size_t)mf * 16 * 512 + _kn); \
    _Pragma("unroll")                                                             \
    for (int nf = 0; nf < 4; nf++) BN[nf] = *(const bf16x8*)(Bbase + (size_t)nf * 16 * 512 + _kn); \
    __builtin_amdgcn_sched_barrier(0);                                            \
    _Pragma("unroll")                                                             \
    for (int mf = 0; mf < 2; mf++)                                                \
      _Pragma("unroll")                                                           \
      for (int nf = 0; nf < 4; nf++)                                              \
        acc[mf][nf] = mfma16(AC[mf], BC[nf], acc[mf][nf]);                        \
  }

__global__ __launch_bounds__(256, 2) void k_out(
    const bf16* __restrict__ AO, const bf16* __restrict__ Wob,
    const float* __restrict__ bo, const float* __restrict__ xm,
    float* __restrict__ out) {
  int n0 = blockIdx.x * 128, m0 = blockIdx.y * 64;
  int wid = threadIdx.x >> 6, lane = threadIdx.x & 63;
  int lr = lane & 15, lg = lane >> 4;
  int mw = m0 + (wid >> 1) * 32, nw = n0 + (wid & 1) * 64;

  const bf16* Abase = Wob + ((size_t)(mw + lr)) * 512 + lg * 8;
  const bf16* Bbase = AO  + ((size_t)(nw + lr)) * 512 + lg * 8;

  f32x4 acc[2][4] = {};
  bf16x8 afA[2], afB[2], bvA[4], bvB[4];
  #pragma unroll
  for (int mf = 0; mf < 2; mf++) afA[mf] = *(const bf16x8*)(Abase + (size_t)mf * 16 * 512);
  #pragma unroll
  for (int nf = 0; nf < 4; nf++) bvA[nf] = *(const bf16x8*)(Bbase + (size_t)nf * 16 * 512);

  for (int k0 = 0; k0 < 512; k0 += 64) {
    OUT_BODY(k0,      afA, bvA, afB, bvB)
    OUT_BODY(k0 + 32, afB, bvB, afA, bvA)
  }

  float bov[2][4];
  #pragma unroll
  for (int mf = 0; mf < 2; mf++)
    #pragma unroll
    for (int r = 0; r < 4; r++) bov[mf][r] = bo[mw + mf * 16 + lg * 4 + r];

  #pragma unroll
  for (int nf = 0; nf < 4; nf++) {
    int tg = nw + nf * 16 + lr;
    int b = tg >> 11, t = tg & 2047;
    float xmv = xm[b * 2048 + t];
    #pragma unroll
    for (int mf = 0; mf < 2; mf++)
      #pragma unroll
      for (int r = 0; r < 4; r++) {
        int d = mw + mf * 16 + lg * 4 + r;
        out[((size_t)b * DM + d) * TT + t] = (acc[mf][nf][r] + bov[mf][r]) * xmv;
      }
  }
}

// ---------------------------------------------------------------- launch
extern "C" void kernel_launch(void* const* d_in, const int* in_sizes, int n_in,
                              void* d_out, int out_size, void* d_ws, size_t ws_size,
                              hipStream_t stream) {
  const float* x     = (const float*)d_in[0];
  const float* ctx   = (const float*)d_in[1];
  const float* xmask = (const float*)d_in[2];
  const float* cmask = (const float*)d_in[3];
  const float* Wq = (const float*)d_in[4];
  const float* bq = (const float*)d_in[5];
  const float* Wk = (const float*)d_in[6];
  const float* bk = (const float*)d_in[7];
  const float* Wv = (const float*)d_in[8];
  const float* bv = (const float*)d_in[9];
  const float* Wo = (const float*)d_in[10];
  const float* bo = (const float*)d_in[11];
  float* out = (float*)d_out;

  char* w = (char*)d_ws;
  // ws layout: xb@0 (->AO), ctxb@8M (->Vf), Qb@16M, Kb@24M, Vb@32M (->Kf),
  //            W@40M, tab@42M..46M   (all offsets as in R3, no growth)
  bf16* xb   = (bf16*)(w + 0);
  bf16* ctxb = (bf16*)(w + 8388608);
  bf16* Qb   = (bf16*)(w + 16777216);
  bf16* Kb   = (bf16*)(w + 25165824);
  bf16* Vb   = (bf16*)(w + 33554432);
  bf16* Wqb  = (bf16*)(w + 41943040);
  bf16* Wkb  = Wqb + 262144;
  bf16* Wvb  = Wqb + 2 * 262144;
  bf16* Wob  = Wqb + 3 * 262144;
  float2* tab = (float2*)(w + 44040192);
  bf16* AO = xb;    // xb dead after k_qkv
  bf16* Vf = ctxb;  // ctxb dead after k_qkv
  bf16* Kf = Vb;    // Vb dead after k_tr_vf

  k_tab<<<dim3(16, 4, 2), 256, 0, stream>>>(xmask, cmask, tab);
  k_cvt_w<<<256, 256, 0, stream>>>(Wq, Wk, Wv, Wo, Wqb);
  k_cvt<<<1024, 256, 0, stream>>>(ctx, ctxb, BB * LL * 512 / 4);
  k_tr_x<<<dim3(TT / 64, DM / 64, BB), 256, 0, stream>>>(x, xb);
  k_qkv<<<dim3(4, 64, 3), 256, 0, stream>>>(xb, ctxb, Wqb, Wkb, Wvb,
                                            bq, bk, bv, tab, Qb, Kb, Vb);
  k_tr_vf<<<dim3(32, NH, BB), 256, 0, stream>>>(Vb, Vf);       // Vb -> Vf (frag order)
  k_repack_k<<<dim3(32, NH, BB), 256, 0, stream>>>(Kb, Kf);    // Kb -> Kf (frag order)
  // ---- diagnostics (outputs overwritten by production dispatch below) ----
  k_attn_t<0, 3><<<512, 256, 0, stream>>>(Qb, Kf, Vf, AO);  // loads+QK   x3
  k_attn_t<1, 2><<<512, 256, 0, stream>>>(Qb, Kf, Vf, AO);  // +softmax   x2
  // ---- production ----
  k_attn_t<2, 1><<<512, 256, 0, stream>>>(Qb, Kf, Vf, AO);
  k_out<<<dim3(64, 8), 256, 0, stream>>>(AO, Wob, bo, xmask, out);
}

// Round 10
// 242.704 us; speedup vs baseline: 1.7935x; 1.7935x over previous
//
#include <hip/hip_runtime.h>

// Problem constants
#define BB 4
#define TT 2048
#define LL 2048
#define DM 512     // d_model
#define AD 512     // attn dim
#define NH 8       // heads
#define HD 64      // head dim
// 1/sqrt(512) * log2(e): Q folded scale so softmax runs in exp2 domain
#define Q_SCALE 0.06375871295f

typedef __bf16 bf16;
typedef __attribute__((ext_vector_type(8))) __bf16 bf16x8;
typedef __attribute__((ext_vector_type(4))) __bf16 bf16x4;
typedef __attribute__((ext_vector_type(4))) float  f32x4;

__device__ __forceinline__ f32x4 mfma16(bf16x8 a, bf16x8 b, f32x4 c) {
  return __builtin_amdgcn_mfma_f32_16x16x32_bf16(a, b, c, 0, 0, 0);
}

__device__ __forceinline__ float fexp2(float x) {
#if __has_builtin(__builtin_amdgcn_exp2f)
  return __builtin_amdgcn_exp2f(x);
#else
  return exp2f(x);
#endif
}

// ================================================================ fragment-pack layout
// All MFMA operands are stored "frag-order" so every fragment load is one
// contiguous 1KB wave burst (R7 PMC: strided gathers were 16-line splits ->
// TA request-rate bound; frag-order cut attn 127->~45us).
// Element (row, k) of a [R x 512] matrix lives at:
//   pack[(row>>4)*8192 + (k>>5)*512 + (((k&31)>>3)*16 + (row&15))*8 + (k&7)]
// A wave's fragment (rows rt*16+lr, k kb*32+lg*8+j) = pack + rt*8192 + kb*512 + lane*8.

// ---------------------------------------------------------------- RoPE cos/sin table
__global__ void k_tab(const float* __restrict__ xm, const float* __restrict__ cm,
                      float2* __restrict__ tab) {
  int which = blockIdx.z, b = blockIdx.y, t0 = blockIdx.x * 128;
  const float* mp = (which ? cm : xm) + b * 2048;
  float s = 0.f;
  for (int i = threadIdx.x; i < 2048; i += 256) s += mp[i];
  #pragma unroll
  for (int o = 32; o > 0; o >>= 1) s += __shfl_down(s, o, 64);
  __shared__ float red[4];
  if ((threadIdx.x & 63) == 0) red[threadIdx.x >> 6] = s;
  __syncthreads();
  float len = red[0] + red[1] + red[2] + red[3];
  float2* tb = tab + ((size_t)(which * 4 + b) * 2048) * 32;
  for (int e = threadIdx.x; e < 128 * 32; e += 256) {
    int tl = e >> 5, i = e & 31;
    float theta = 10.f * __expf(-(float)i * 0.28782313662425576f);
    float f = ((float)(t0 + tl) / len) * theta;
    float sn, cs;
    __sincosf(f, &sn, &cs);
    tb[(size_t)(t0 + tl) * 32 + i] = make_float2(cs, sn);
  }
}

// ---------------------------------------------------------------- generic f32[Rx512] -> bf16 frag-pack
// grid (R/64, 512/64); 64x64 tile. Coalesced float4 reads, contiguous 16B frag writes.
__global__ void k_packA(const float* __restrict__ src, bf16* __restrict__ dst) {
  __shared__ float tile[64][68];
  int row0 = blockIdx.x * 64, k0 = blockIdx.y * 64;
  int t = threadIdx.x;
  int rl = t >> 2, cg = t & 3;
  #pragma unroll
  for (int i = 0; i < 4; i++) {
    float4 v = *(const float4*)(src + (size_t)(row0 + rl) * 512 + k0 + cg * 16 + i * 4);
    *(float4*)&tile[rl][cg * 16 + i * 4] = v;
  }
  __syncthreads();
  #pragma unroll
  for (int i = 0; i < 2; i++) {
    int v = i * 256 + t;                  // (rt_l<<7)|(kb_l<<6)|(lg<<4)|lr
    int rt_l = v >> 7, kb_l = (v >> 6) & 1, lg = (v >> 4) & 3, lr = v & 15;
    const float* sp = &tile[rt_l * 16 + lr][kb_l * 32 + lg * 8];
    bf16x8 o;
    #pragma unroll
    for (int j = 0; j < 8; j++) o[j] = (bf16)sp[j];
    *(bf16x8*)(dst + (size_t)((row0 >> 4) + rt_l) * 8192
                   + ((k0 >> 5) + kb_l) * 512 + (lg * 16 + lr) * 8) = o;
  }
}

// ---------------------------------------------------------------- x (B,DM,T) f32 -> xpack frag-order bf16
// rows = b*2048+t, k = dm. Transposing pack (x is dm-major).
__global__ void k_tr_x(const float* __restrict__ x, bf16* __restrict__ xp) {
  __shared__ float tile[64][65];   // [dm_local][t_local]
  int t0 = blockIdx.x * 64, m0 = blockIdx.y * 64, b = blockIdx.z;
  int c = threadIdx.x & 63, rg = threadIdx.x >> 6;
  #pragma unroll
  for (int i = 0; i < 16; i++) {
    int r = rg * 16 + i;
    tile[r][c] = x[((size_t)b * DM + (m0 + r)) * TT + t0 + c];
  }
  __syncthreads();
  int rb = b * 128 + (t0 >> 4);    // global row-tile base
  #pragma unroll
  for (int i = 0; i < 2; i++) {
    int v = i * 256 + threadIdx.x;
    int rt_l = v >> 7, kb_l = (v >> 6) & 1, lg = (v >> 4) & 3, lr = v & 15;
    bf16x8 o;
    #pragma unroll
    for (int j = 0; j < 8; j++) o[j] = (bf16)tile[kb_l * 32 + lg * 8 + j][rt_l * 16 + lr];
    *(bf16x8*)(xp + (size_t)(rb + rt_l) * 8192
                  + ((m0 >> 5) + kb_l) * 512 + (lg * 16 + lr) * 8) = o;
  }
}

// ---------------------------------------------------------------- V (B,L,AD) bf16 -> Vf fragment-order
// Vf[b][h][ltile][f=nf*2+ks][lane][8]: elem j = V[l0+lg*8+ks*32+j][d=nf*16+lr].
__global__ void k_tr_vf(const bf16* __restrict__ Vb, bf16* __restrict__ Vf) {
  __shared__ bf16 vtile[64][72];   // [l][d], padded
  int l0b = blockIdx.x, h = blockIdx.y, b = blockIdx.z;
  int t = threadIdx.x;
  int l = t >> 2, c = t & 3;
  const bf16* src = Vb + ((size_t)(b * 2048 + l0b * 64 + l)) * 512 + h * 64 + c * 16;
  *(bf16x8*)&vtile[l][c * 16]     = *(const bf16x8*)(src);
  *(bf16x8*)&vtile[l][c * 16 + 8] = *(const bf16x8*)(src + 8);
  __syncthreads();
  bf16* dst = Vf + ((size_t)((b * NH + h) * 32 + l0b)) * 4096;
  #pragma unroll
  for (int i = 0; i < 2; i++) {
    int o = (i * 256 + t) * 8;
    int f = o >> 9, lid = (o & 511) >> 3;
    int nf = f >> 1, ks = f & 1, lg = lid >> 4, lr = lid & 15;
    bf16x8 v8;
    #pragma unroll
    for (int j = 0; j < 8; j++) v8[j] = vtile[lg * 8 + ks * 32 + j][nf * 16 + lr];
    *(bf16x8*)(dst + o) = v8;
  }
}

// ---------------------------------------------------------------- K (B,L,AD) bf16 -> Kf fragment-order
// Kf[b][h][ltile][f=lf*2+ks][lane][8]: elem j = K[l0+lf*16+lr][k=lg*8+ks*32+j].
__global__ void k_repack_k(const bf16* __restrict__ Kb, bf16* __restrict__ Kf) {
  int l0b = blockIdx.x, h = blockIdx.y, b = blockIdx.z;
  int t = threadIdx.x;
  bf16* dst = Kf + ((size_t)((b * NH + h) * 32 + l0b)) * 4096;
  #pragma unroll
  for (int i = 0; i < 2; i++) {
    int o = (i * 256 + t) * 8;
    int f = o >> 9, lid = (o & 511) >> 3;
    int lf = f >> 1, ks = f & 1, lg = lid >> 4, lr = lid & 15;
    const bf16* src = Kb + ((size_t)(b * 2048 + l0b * 64 + lf * 16 + lr)) * 512
                         + h * 64 + lg * 8 + ks * 32;
    *(bf16x8*)(dst + o) = *(const bf16x8*)(src);
  }
}

// ---------------------------------------------------------------- fused QKV projection GEMM + RoPE epilogue
// All operand loads are frag-pack 1KB bursts. 2-deep ping-pong kept.
#define QKV_BODY(K0, AC, BC, AN, BN)                                              \
  {                                                                               \
    int _kb = (((K0) + 32) & 511) >> 5;                                           \
    _Pragma("unroll")                                                             \
    for (int mf = 0; mf < 4; mf++) AN[mf] = *(const bf16x8*)(Abase + mf * 8192 + _kb * 512); \
    _Pragma("unroll")                                                             \
    for (int nf = 0; nf < 4; nf++) BN[nf] = *(const bf16x8*)(Bbase + nf * 8192 + _kb * 512); \
    __builtin_amdgcn_sched_barrier(0);                                            \
    _Pragma("unroll")                                                             \
    for (int mf = 0; mf < 4; mf++)                                                \
      _Pragma("unroll")                                                           \
      for (int nf = 0; nf < 4; nf++)                                              \
        acc[mf][nf] = mfma16(AC[mf], BC[nf], acc[mf][nf]);                        \
  }

__global__ __launch_bounds__(256, 3) void k_qkv(
    const bf16* __restrict__ xp, const bf16* __restrict__ cp,
    const bf16* __restrict__ Wp,
    const float* __restrict__ bq, const float* __restrict__ bk, const float* __restrict__ bv,
    const float2* __restrict__ tab,
    bf16* __restrict__ Qb, bf16* __restrict__ Kb, bf16* __restrict__ Vb) {
  int proj = blockIdx.z;
  const bf16* A     = (proj == 0) ? xp : cp;
  const float* bias = (proj == 0) ? bq : (proj == 1 ? bk : bv);
  bf16* out         = (proj == 0) ? Qb : (proj == 1 ? Kb : Vb);

  int m0 = blockIdx.y * 128, n0 = blockIdx.x * 128;
  int wid = threadIdx.x >> 6, lane = threadIdx.x & 63;
  int lr = lane & 15, lg = lane >> 4;
  int mw = m0 + (wid >> 1) * 64, nw = n0 + (wid & 1) * 64;

  const bf16* Abase = A  + (size_t)(mw >> 4) * 8192 + lane * 8;
  const bf16* Bbase = Wp + (size_t)proj * 262144 + (size_t)(nw >> 4) * 8192 + lane * 8;

  f32x4 acc[4][4] = {};
  bf16x8 afA[4], afB[4], bvA[4], bvB[4];
  #pragma unroll
  for (int mf = 0; mf < 4; mf++) afA[mf] = *(const bf16x8*)(Abase + mf * 8192);
  #pragma unroll
  for (int nf = 0; nf < 4; nf++) bvA[nf] = *(const bf16x8*)(Bbase + nf * 8192);

  for (int k0 = 0; k0 < 512; k0 += 64) {
    QKV_BODY(k0,      afA, bvA, afB, bvB)
    QKV_BODY(k0 + 32, afB, bvB, afA, bvA)
  }

  if (proj < 2) {
    float qs = (proj == 0) ? Q_SCALE : 1.0f;
    const float2* tb = tab + (size_t)proj * 4 * 2048 * 32;
    #pragma unroll
    for (int mf = 0; mf < 4; mf++)
      #pragma unroll
      for (int r = 0; r < 4; r++) {
        int row = mw + mf * 16 + lg * 4 + r;
        int b = row >> 11, t = row & 2047;
        const float2* trow = tb + ((size_t)b * 2048 + t) * 32;
        #pragma unroll
        for (int nf = 0; nf < 2; nf++) {
          int i = nf * 16 + lr;
          float2 cs = trow[i];
          float x1 = acc[mf][nf][r]     + bias[nw + nf * 16 + lr];
          float x2 = acc[mf][nf + 2][r] + bias[nw + (nf + 2) * 16 + lr];
          out[(size_t)row * 512 + nw + nf * 16 + lr]       = (bf16)((x1 * cs.x - x2 * cs.y) * qs);
          out[(size_t)row * 512 + nw + (nf + 2) * 16 + lr] = (bf16)((x1 * cs.y + x2 * cs.x) * qs);
        }
      }
  } else {
    #pragma unroll
    for (int nf = 0; nf < 4; nf++) {
      float bb = bias[nw + nf * 16 + lr];
      #pragma unroll
      for (int mf = 0; mf < 4; mf++)
        #pragma unroll
        for (int r = 0; r < 4; r++) {
          int row = mw + mf * 16 + lg * 4 + r;
          out[(size_t)row * 512 + nw + nf * 16 + lr] = (bf16)(acc[mf][nf][r] + bb);
        }
    }
  }
}

// ---------------------------------------------------------------- flash attention
// T-tile 64 (grid 1024 = 2x TLP, 4 blocks/CU): R7 showed attn ~45us with burst loads
// still latency/L2-limited at 2 blocks/CU. 4 waves x 16 q-rows, swapped QK^T,
// frag-order K/V (1KB bursts), no ping-pong (TLP hides latency; VGPR budget <=128).
__global__ __launch_bounds__(256, 4) void k_attn(
    const bf16* __restrict__ Qb, const bf16* __restrict__ Kf, const bf16* __restrict__ Vf,
    bf16* __restrict__ AO) {
  int bid = blockIdx.x;
  int sw = (bid & 7) * 128 + (bid >> 3);   // bijective XCD swizzle (1024 = 8*128)
  int qt = sw & 31, h = (sw >> 5) & 7, b = sw >> 8;

  int wid = threadIdx.x >> 6, lane = threadIdx.x & 63;
  int lr = lane & 15, lg = lane >> 4;
  int t0 = qt * 64 + wid * 16;

  __shared__ bf16 Plds[4][16 * 64];
  bf16* myP = &Plds[wid][0];

  // Q fragments (B-operand of swapped QK^T): t = t0+lr, k = lg*8+ks*32+j
  const bf16* Qbase = Qb + ((size_t)(b * 2048 + t0 + lr)) * AD + h * HD + lg * 8;
  bf16x8 qf[2];
  #pragma unroll
  for (int ks = 0; ks < 2; ks++)
    qf[ks] = *(const bf16x8*)(Qbase + ks * 32);

  bf16x8 ones8;
  #pragma unroll
  for (int j = 0; j < 8; j++) ones8[j] = (bf16)1.0f;

  float mrow = -1e30f;            // running max for row t = t0 + lr
  f32x4 oacc[4] = {};             // t = t0+lg*4+r, d = nf*16+lr
  f32x4 oext = {};                // running softmax denominator

  const bf16* KfB = Kf + ((size_t)((b * NH + h) * 32)) * 4096 + lane * 8;
  const bf16* VfB = Vf + ((size_t)((b * NH + h) * 32)) * 4096 + lane * 8;

  #pragma unroll 1
  for (int tile = 0; tile < 32; tile++) {
    const bf16* KfT = KfB + (size_t)tile * 4096;
    const bf16* VfT = VfB + (size_t)tile * 4096;
    bf16x8 kf[4][2], vf[4][2];
    #pragma unroll
    for (int nf = 0; nf < 4; nf++)
      #pragma unroll
      for (int ks = 0; ks < 2; ks++)
        vf[nf][ks] = *(const bf16x8*)(VfT + (nf * 2 + ks) * 512);
    #pragma unroll
    for (int lf = 0; lf < 4; lf++)
      #pragma unroll
      for (int ks = 0; ks < 2; ks++)
        kf[lf][ks] = *(const bf16x8*)(KfT + (lf * 2 + ks) * 512);
    __builtin_amdgcn_sched_barrier(0);

    // S^T = K Q^T: sacc[lf][r] = S[t=t0+lr][l = tile*64 + lf*16+lg*4+r]
    f32x4 sacc[4] = {};
    __builtin_amdgcn_s_setprio(1);
    #pragma unroll
    for (int lf = 0; lf < 4; lf++)
      #pragma unroll
      for (int ks = 0; ks < 2; ks++)
        sacc[lf] = mfma16(kf[lf][ks], qf[ks], sacc[lf]);
    __builtin_amdgcn_s_setprio(0);

    // row max: 16 in-lane + butterfly across the 4 lg groups
    float mm = fmaxf(
        fmaxf(fmaxf(fmaxf(sacc[0][0], sacc[0][1]), fmaxf(sacc[0][2], sacc[0][3])),
              fmaxf(fmaxf(sacc[1][0], sacc[1][1]), fmaxf(sacc[1][2], sacc[1][3]))),
        fmaxf(fmaxf(fmaxf(sacc[2][0], sacc[2][1]), fmaxf(sacc[2][2], sacc[2][3])),
              fmaxf(fmaxf(sacc[3][0], sacc[3][1]), fmaxf(sacc[3][2], sacc[3][3]))));
    mm = fmaxf(mm, __shfl_xor(mm, 16, 64));
    mm = fmaxf(mm, __shfl_xor(mm, 32, 64));

    // T13 defer-max, wave-uniform branch
    if (__any(mm > mrow + 8.f)) {
      float mn = fmaxf(mrow, mm);
      float co = fexp2(mrow - mn);
      mrow = mn;
      #pragma unroll
      for (int r = 0; r < 4; r++) {
        float cc = __shfl(co, lg * 4 + r, 16);   // corr of row t0+lg*4+r
        oext[r] *= cc;
        #pragma unroll
        for (int nf = 0; nf < 4; nf++) oacc[nf][r] *= cc;
      }
    }

    // P = exp2(S - m) -> LDS (bf16x4, XOR-swizzled rows)
    #pragma unroll
    for (int lf = 0; lf < 4; lf++) {
      bf16x4 p4;
      #pragma unroll
      for (int r = 0; r < 4; r++)
        p4[r] = (bf16)fexp2(sacc[lf][r] - mrow);
      int byte = lr * 128 + (lf * 16 + lg * 4) * 2;
      byte ^= (lr & 7) << 4;
      *(bf16x4*)((char*)myP + byte) = p4;
    }

    // PV (+ ones column): A = P from LDS (m = t = lr rows, k = l)
    bf16x8 pa[2];
    #pragma unroll
    for (int ks = 0; ks < 2; ks++) {
      int byte = lr * 128 + (lg * 8 + ks * 32) * 2;
      byte ^= (lr & 7) << 4;
      pa[ks] = *(const bf16x8*)((const char*)myP + byte);
    }
    __builtin_amdgcn_s_setprio(1);
    #pragma unroll
    for (int nf = 0; nf < 4; nf++)
      #pragma unroll
      for (int ks = 0; ks < 2; ks++)
        oacc[nf] = mfma16(pa[ks], vf[nf][ks], oacc[nf]);
    #pragma unroll
    for (int ks = 0; ks < 2; ks++)
      oext = mfma16(pa[ks], ones8, oext);
    __builtin_amdgcn_s_setprio(0);
  }

  // epilogue: normalize, store AO (B,T,AD) bf16
  #pragma unroll
  for (int r = 0; r < 4; r++) {
    float inv = 1.0f / fmaxf(oext[r], 1e-35f);
    int t = t0 + lg * 4 + r;
    #pragma unroll
    for (int nf = 0; nf < 4; nf++)
      AO[((size_t)b * 2048 + t) * AD + h * HD + nf * 16 + lr] =
          (bf16)(oacc[nf][r] * inv);
  }
}

// ---------------------------------------------------------------- output projection, transposed store
// A = Wo (frag-pack bursts); B = AO (row-major, strided — candidate next round).
#define OUT_BODY(K0, AC, BC, AN, BN)                                              \
  {                                                                               \
    int _kn = ((K0) + 32) & 511;                                                  \
    int _kb = _kn >> 5;                                                           \
    _Pragma("unroll")                                                             \
    for (int mf = 0; mf < 2; mf++) AN[mf] = *(const bf16x8*)(Abase + mf * 8192 + _kb * 512); \
    _Pragma("unroll")                                                             \
    for (int nf = 0; nf < 4; nf++) BN[nf] = *(const bf16x8*)(Bbase + (size_t)nf * 16 * 512 + _kn); \
    __builtin_amdgcn_sched_barrier(0);                                            \
    _Pragma("unroll")                                                             \
    for (int mf = 0; mf < 2; mf++)                                                \
      _Pragma("unroll")                                                           \
      for (int nf = 0; nf < 4; nf++)                                              \
        acc[mf][nf] = mfma16(AC[mf], BC[nf], acc[mf][nf]);                        \
  }

__global__ __launch_bounds__(256, 2) void k_out(
    const bf16* __restrict__ AO, const bf16* __restrict__ Wp,
    const float* __restrict__ bo, const float* __restrict__ xm,
    float* __restrict__ out) {
  int n0 = blockIdx.x * 128, m0 = blockIdx.y * 64;
  int wid = threadIdx.x >> 6, lane = threadIdx.x & 63;
  int lr = lane & 15, lg = lane >> 4;
  int mw = m0 + (wid >> 1) * 32, nw = n0 + (wid & 1) * 64;

  const bf16* Abase = Wp + 3 * 262144 + (size_t)(mw >> 4) * 8192 + lane * 8;
  const bf16* Bbase = AO + ((size_t)(nw + lr)) * 512 + lg * 8;

  f32x4 acc[2][4] = {};
  bf16x8 afA[2], afB[2], bvA[4], bvB[4];
  #pragma unroll
  for (int mf = 0; mf < 2; mf++) afA[mf] = *(const bf16x8*)(Abase + mf * 8192);
  #pragma unroll
  for (int nf = 0; nf < 4; nf++) bvA[nf] = *(const bf16x8*)(Bbase + (size_t)nf * 16 * 512);

  for (int k0 = 0; k0 < 512; k0 += 64) {
    OUT_BODY(k0,      afA, bvA, afB, bvB)
    OUT_BODY(k0 + 32, afB, bvB, afA, bvA)
  }

  float bov[2][4];
  #pragma unroll
  for (int mf = 0; mf < 2; mf++)
    #pragma unroll
    for (int r = 0; r < 4; r++) bov[mf][r] = bo[mw + mf * 16 + lg * 4 + r];

  #pragma unroll
  for (int nf = 0; nf < 4; nf++) {
    int tg = nw + nf * 16 + lr;
    int b = tg >> 11, t = tg & 2047;
    float xmv = xm[b * 2048 + t];
    #pragma unroll
    for (int mf = 0; mf < 2; mf++)
      #pragma unroll
      for (int r = 0; r < 4; r++) {
        int d = mw + mf * 16 + lg * 4 + r;
        out[((size_t)b * DM + d) * TT + t] = (acc[mf][nf][r] + bov[mf][r]) * xmv;
      }
  }
}

// ---------------------------------------------------------------- launch
extern "C" void kernel_launch(void* const* d_in, const int* in_sizes, int n_in,
                              void* d_out, int out_size, void* d_ws, size_t ws_size,
                              hipStream_t stream) {
  const float* x     = (const float*)d_in[0];
  const float* ctx   = (const float*)d_in[1];
  const float* xmask = (const float*)d_in[2];
  const float* cmask = (const float*)d_in[3];
  const float* Wq = (const float*)d_in[4];
  const float* bq = (const float*)d_in[5];
  const float* Wk = (const float*)d_in[6];
  const float* bk = (const float*)d_in[7];
  const float* Wv = (const float*)d_in[8];
  const float* bv = (const float*)d_in[9];
  const float* Wo = (const float*)d_in[10];
  const float* bo = (const float*)d_in[11];
  float* out = (float*)d_out;

  char* w = (char*)d_ws;
  // ws layout: xp@0 (->AO), cp@8M (->Vf), Qb@16M, Kb@24M, Vb@32M (->Kf),
  //            Wp@40M (2MB frag-pack x4), tab@42M..46M
  bf16* xp   = (bf16*)(w + 0);
  bf16* cp   = (bf16*)(w + 8388608);
  bf16* Qb   = (bf16*)(w + 16777216);
  bf16* Kb   = (bf16*)(w + 25165824);
  bf16* Vb   = (bf16*)(w + 33554432);
  bf16* Wp   = (bf16*)(w + 41943040);
  float2* tab = (float2*)(w + 44040192);
  bf16* AO = xp;    // xp dead after k_qkv
  bf16* Vf = cp;    // cp dead after k_qkv
  bf16* Kf = Vb;    // Vb dead after k_tr_vf

  k_tab<<<dim3(16, 4, 2), 256, 0, stream>>>(xmask, cmask, tab);
  k_packA<<<dim3(8, 8),   256, 0, stream>>>(Wq, Wp);
  k_packA<<<dim3(8, 8),   256, 0, stream>>>(Wk, Wp + 262144);
  k_packA<<<dim3(8, 8),   256, 0, stream>>>(Wv, Wp + 2 * 262144);
  k_packA<<<dim3(8, 8),   256, 0, stream>>>(Wo, Wp + 3 * 262144);
  k_packA<<<dim3(128, 8), 256, 0, stream>>>(ctx, cp);
  k_tr_x<<<dim3(TT / 64, DM / 64, BB), 256, 0, stream>>>(x, xp);
  k_qkv<<<dim3(4, 64, 3), 256, 0, stream>>>(xp, cp, Wp, bq, bk, bv, tab, Qb, Kb, Vb);
  k_tr_vf<<<dim3(32, NH, BB), 256, 0, stream>>>(Vb, Vf);
  k_repack_k<<<dim3(32, NH, BB), 256, 0, stream>>>(Kb, Kf);
  k_attn<<<1024, 256, 0, stream>>>(Qb, Kf, Vf, AO);
  k_out<<<dim3(64, 8), 256, 0, stream>>>(AO, Wp, bo, xmask, out);
}

// Round 11
// 226.220 us; speedup vs baseline: 1.9242x; 1.0729x over previous
//
#include <hip/hip_runtime.h>

// Problem constants
#define BB 4
#define TT 2048
#define LL 2048
#define DM 512     // d_model
#define AD 512     // attn dim
#define NH 8       // heads
#define HD 64      // head dim
// 1/sqrt(512) * log2(e): Q folded scale so softmax runs in exp2 domain
#define Q_SCALE 0.06375871295f

typedef __bf16 bf16;
typedef __attribute__((ext_vector_type(8))) __bf16 bf16x8;
typedef __attribute__((ext_vector_type(4))) __bf16 bf16x4;
typedef __attribute__((ext_vector_type(4))) float  f32x4;

__device__ __forceinline__ f32x4 mfma16(bf16x8 a, bf16x8 b, f32x4 c) {
  return __builtin_amdgcn_mfma_f32_16x16x32_bf16(a, b, c, 0, 0, 0);
}

__device__ __forceinline__ float fexp2(float x) {
#if __has_builtin(__builtin_amdgcn_exp2f)
  return __builtin_amdgcn_exp2f(x);
#else
  return exp2f(x);
#endif
}

// ================================================================ fragment-pack layout
// All MFMA operands stored "frag-order": every fragment load is one contiguous
// 1KB wave burst (R7 PMC: strided gathers were 16-line splits -> TA-bound).
// R10 lesson: q-rows/wave (Q-reuse) divides total K/V volume; 32 rows/wave +
// K ping-pong (R7 structure) measured faster than 16 rows/wave + 2x TLP (76us).

// ---------------------------------------------------------------- RoPE cos/sin table
__global__ void k_tab(const float* __restrict__ xm, const float* __restrict__ cm,
                      float2* __restrict__ tab) {
  int which = blockIdx.z, b = blockIdx.y, t0 = blockIdx.x * 128;
  const float* mp = (which ? cm : xm) + b * 2048;
  float s = 0.f;
  for (int i = threadIdx.x; i < 2048; i += 256) s += mp[i];
  #pragma unroll
  for (int o = 32; o > 0; o >>= 1) s += __shfl_down(s, o, 64);
  __shared__ float red[4];
  if ((threadIdx.x & 63) == 0) red[threadIdx.x >> 6] = s;
  __syncthreads();
  float len = red[0] + red[1] + red[2] + red[3];
  float2* tb = tab + ((size_t)(which * 4 + b) * 2048) * 32;
  for (int e = threadIdx.x; e < 128 * 32; e += 256) {
    int tl = e >> 5, i = e & 31;
    float theta = 10.f * __expf(-(float)i * 0.28782313662425576f);
    float f = ((float)(t0 + tl) / len) * theta;
    float sn, cs;
    __sincosf(f, &sn, &cs);
    tb[(size_t)(t0 + tl) * 32 + i] = make_float2(cs, sn);
  }
}

// ---------------------------------------------------------------- generic f32[Rx512] -> bf16 frag-pack
__global__ void k_packA(const float* __restrict__ src, bf16* __restrict__ dst) {
  __shared__ float tile[64][68];
  int row0 = blockIdx.x * 64, k0 = blockIdx.y * 64;
  int t = threadIdx.x;
  int rl = t >> 2, cg = t & 3;
  #pragma unroll
  for (int i = 0; i < 4; i++) {
    float4 v = *(const float4*)(src + (size_t)(row0 + rl) * 512 + k0 + cg * 16 + i * 4);
    *(float4*)&tile[rl][cg * 16 + i * 4] = v;
  }
  __syncthreads();
  #pragma unroll
  for (int i = 0; i < 2; i++) {
    int v = i * 256 + t;                  // (rt_l<<7)|(kb_l<<6)|(lg<<4)|lr
    int rt_l = v >> 7, kb_l = (v >> 6) & 1, lg = (v >> 4) & 3, lr = v & 15;
    const float* sp = &tile[rt_l * 16 + lr][kb_l * 32 + lg * 8];
    bf16x8 o;
    #pragma unroll
    for (int j = 0; j < 8; j++) o[j] = (bf16)sp[j];
    *(bf16x8*)(dst + (size_t)((row0 >> 4) + rt_l) * 8192
                   + ((k0 >> 5) + kb_l) * 512 + (lg * 16 + lr) * 8) = o;
  }
}

// ---------------------------------------------------------------- x (B,DM,T) f32 -> xpack frag-order bf16
__global__ void k_tr_x(const float* __restrict__ x, bf16* __restrict__ xp) {
  __shared__ float tile[64][65];   // [dm_local][t_local]
  int t0 = blockIdx.x * 64, m0 = blockIdx.y * 64, b = blockIdx.z;
  int c = threadIdx.x & 63, rg = threadIdx.x >> 6;
  #pragma unroll
  for (int i = 0; i < 16; i++) {
    int r = rg * 16 + i;
    tile[r][c] = x[((size_t)b * DM + (m0 + r)) * TT + t0 + c];
  }
  __syncthreads();
  int rb = b * 128 + (t0 >> 4);    // global row-tile base
  #pragma unroll
  for (int i = 0; i < 2; i++) {
    int v = i * 256 + threadIdx.x;
    int rt_l = v >> 7, kb_l = (v >> 6) & 1, lg = (v >> 4) & 3, lr = v & 15;
    bf16x8 o;
    #pragma unroll
    for (int j = 0; j < 8; j++) o[j] = (bf16)tile[kb_l * 32 + lg * 8 + j][rt_l * 16 + lr];
    *(bf16x8*)(xp + (size_t)(rb + rt_l) * 8192
                  + ((m0 >> 5) + kb_l) * 512 + (lg * 16 + lr) * 8) = o;
  }
}

// ---------------------------------------------------------------- V (B,L,AD) bf16 -> Vf fragment-order
__global__ void k_tr_vf(const bf16* __restrict__ Vb, bf16* __restrict__ Vf) {
  __shared__ bf16 vtile[64][72];   // [l][d], padded
  int l0b = blockIdx.x, h = blockIdx.y, b = blockIdx.z;
  int t = threadIdx.x;
  int l = t >> 2, c = t & 3;
  const bf16* src = Vb + ((size_t)(b * 2048 + l0b * 64 + l)) * 512 + h * 64 + c * 16;
  *(bf16x8*)&vtile[l][c * 16]     = *(const bf16x8*)(src);
  *(bf16x8*)&vtile[l][c * 16 + 8] = *(const bf16x8*)(src + 8);
  __syncthreads();
  bf16* dst = Vf + ((size_t)((b * NH + h) * 32 + l0b)) * 4096;
  #pragma unroll
  for (int i = 0; i < 2; i++) {
    int o = (i * 256 + t) * 8;
    int f = o >> 9, lid = (o & 511) >> 3;
    int nf = f >> 1, ks = f & 1, lg = lid >> 4, lr = lid & 15;
    bf16x8 v8;
    #pragma unroll
    for (int j = 0; j < 8; j++) v8[j] = vtile[lg * 8 + ks * 32 + j][nf * 16 + lr];
    *(bf16x8*)(dst + o) = v8;
  }
}

// ---------------------------------------------------------------- K (B,L,AD) bf16 -> Kf fragment-order
__global__ void k_repack_k(const bf16* __restrict__ Kb, bf16* __restrict__ Kf) {
  int l0b = blockIdx.x, h = blockIdx.y, b = blockIdx.z;
  int t = threadIdx.x;
  bf16* dst = Kf + ((size_t)((b * NH + h) * 32 + l0b)) * 4096;
  #pragma unroll
  for (int i = 0; i < 2; i++) {
    int o = (i * 256 + t) * 8;
    int f = o >> 9, lid = (o & 511) >> 3;
    int lf = f >> 1, ks = f & 1, lg = lid >> 4, lr = lid & 15;
    const bf16* src = Kb + ((size_t)(b * 2048 + l0b * 64 + lf * 16 + lr)) * 512
                         + h * 64 + lg * 8 + ks * 32;
    *(bf16x8*)(dst + o) = *(const bf16x8*)(src);
  }
}

// ---------------------------------------------------------------- fused QKV projection GEMM + RoPE epilogue
#define QKV_BODY(K0, AC, BC, AN, BN)                                              \
  {                                                                               \
    int _kb = (((K0) + 32) & 511) >> 5;                                           \
    _Pragma("unroll")                                                             \
    for (int mf = 0; mf < 4; mf++) AN[mf] = *(const bf16x8*)(Abase + mf * 8192 + _kb * 512); \
    _Pragma("unroll")                                                             \
    for (int nf = 0; nf < 4; nf++) BN[nf] = *(const bf16x8*)(Bbase + nf * 8192 + _kb * 512); \
    __builtin_amdgcn_sched_barrier(0);                                            \
    _Pragma("unroll")                                                             \
    for (int mf = 0; mf < 4; mf++)                                                \
      _Pragma("unroll")                                                           \
      for (int nf = 0; nf < 4; nf++)                                              \
        acc[mf][nf] = mfma16(AC[mf], BC[nf], acc[mf][nf]);                        \
  }

__global__ __launch_bounds__(256, 3) void k_qkv(
    const bf16* __restrict__ xp, const bf16* __restrict__ cp,
    const bf16* __restrict__ Wp,
    const float* __restrict__ bq, const float* __restrict__ bk, const float* __restrict__ bv,
    const float2* __restrict__ tab,
    bf16* __restrict__ Qb, bf16* __restrict__ Kb, bf16* __restrict__ Vb) {
  int proj = blockIdx.z;
  const bf16* A     = (proj == 0) ? xp : cp;
  const float* bias = (proj == 0) ? bq : (proj == 1 ? bk : bv);
  bf16* out         = (proj == 0) ? Qb : (proj == 1 ? Kb : Vb);

  int m0 = blockIdx.y * 128, n0 = blockIdx.x * 128;
  int wid = threadIdx.x >> 6, lane = threadIdx.x & 63;
  int lr = lane & 15, lg = lane >> 4;
  int mw = m0 + (wid >> 1) * 64, nw = n0 + (wid & 1) * 64;

  const bf16* Abase = A  + (size_t)(mw >> 4) * 8192 + lane * 8;
  const bf16* Bbase = Wp + (size_t)proj * 262144 + (size_t)(nw >> 4) * 8192 + lane * 8;

  f32x4 acc[4][4] = {};
  bf16x8 afA[4], afB[4], bvA[4], bvB[4];
  #pragma unroll
  for (int mf = 0; mf < 4; mf++) afA[mf] = *(const bf16x8*)(Abase + mf * 8192);
  #pragma unroll
  for (int nf = 0; nf < 4; nf++) bvA[nf] = *(const bf16x8*)(Bbase + nf * 8192);

  for (int k0 = 0; k0 < 512; k0 += 64) {
    QKV_BODY(k0,      afA, bvA, afB, bvB)
    QKV_BODY(k0 + 32, afB, bvB, afA, bvA)
  }

  if (proj < 2) {
    float qs = (proj == 0) ? Q_SCALE : 1.0f;
    const float2* tb = tab + (size_t)proj * 4 * 2048 * 32;
    #pragma unroll
    for (int mf = 0; mf < 4; mf++)
      #pragma unroll
      for (int r = 0; r < 4; r++) {
        int row = mw + mf * 16 + lg * 4 + r;
        int b = row >> 11, t = row & 2047;
        const float2* trow = tb + ((size_t)b * 2048 + t) * 32;
        #pragma unroll
        for (int nf = 0; nf < 2; nf++) {
          int i = nf * 16 + lr;
          float2 cs = trow[i];
          float x1 = acc[mf][nf][r]     + bias[nw + nf * 16 + lr];
          float x2 = acc[mf][nf + 2][r] + bias[nw + (nf + 2) * 16 + lr];
          out[(size_t)row * 512 + nw + nf * 16 + lr]       = (bf16)((x1 * cs.x - x2 * cs.y) * qs);
          out[(size_t)row * 512 + nw + (nf + 2) * 16 + lr] = (bf16)((x1 * cs.y + x2 * cs.x) * qs);
        }
      }
  } else {
    #pragma unroll
    for (int nf = 0; nf < 4; nf++) {
      float bb = bias[nw + nf * 16 + lr];
      #pragma unroll
      for (int mf = 0; mf < 4; mf++)
        #pragma unroll
        for (int r = 0; r < 4; r++) {
          int row = mw + mf * 16 + lg * 4 + r;
          out[(size_t)row * 512 + nw + nf * 16 + lr] = (bf16)(acc[mf][nf][r] + bb);
        }
    }
  }
}

// ---------------------------------------------------------------- flash attention (R7 structure, measured-best)
// T-tile 128: 4 waves x 32 q-rows (2x Q-reuse halves K/V volume vs R10's 76us).
// K ping-pong one tile ahead; V issued at body top (vmcnt order: pre-QK wait is
// a no-op since K_cur landed last body; pre-PV leaves K_next in flight).
// Swapped QK^T; exp2-domain softmax; ones-column denominator; defer-max THR=8.
#define ATT_BODY(TCUR, KC, KN)                                                    \
  {                                                                               \
    const bf16* VfT = VfB + (size_t)(TCUR) * 4096;                                \
    const bf16* KfN = KfB + (size_t)(((TCUR) + 1) & 31) * 4096;                   \
    _Pragma("unroll")                                                             \
    for (int nf = 0; nf < 4; nf++)                                                \
      _Pragma("unroll")                                                           \
      for (int ks = 0; ks < 2; ks++)                                              \
        vf[nf][ks] = *(const bf16x8*)(VfT + (nf * 2 + ks) * 512);                 \
    _Pragma("unroll")                                                             \
    for (int lf = 0; lf < 4; lf++)                                                \
      _Pragma("unroll")                                                           \
      for (int ks = 0; ks < 2; ks++)                                              \
        KN[lf][ks] = *(const bf16x8*)(KfN + (lf * 2 + ks) * 512);                 \
    __builtin_amdgcn_sched_barrier(0);                                            \
    f32x4 sacc[4][2] = {};                                                        \
    __builtin_amdgcn_s_setprio(1);                                                \
    _Pragma("unroll")                                                             \
    for (int lf = 0; lf < 4; lf++)                                                \
      _Pragma("unroll")                                                           \
      for (int tf = 0; tf < 2; tf++)                                              \
        _Pragma("unroll")                                                         \
        for (int ks = 0; ks < 2; ks++)                                            \
          sacc[lf][tf] = mfma16(KC[lf][ks], qf[tf][ks], sacc[lf][tf]);            \
    __builtin_amdgcn_s_setprio(0);                                                \
    float mx[2];                                                                  \
    _Pragma("unroll")                                                             \
    for (int tf = 0; tf < 2; tf++) {                                              \
      float mm = fmaxf(                                                           \
          fmaxf(fmaxf(fmaxf(sacc[0][tf][0], sacc[0][tf][1]), fmaxf(sacc[0][tf][2], sacc[0][tf][3])), \
                fmaxf(fmaxf(sacc[1][tf][0], sacc[1][tf][1]), fmaxf(sacc[1][tf][2], sacc[1][tf][3]))), \
          fmaxf(fmaxf(fmaxf(sacc[2][tf][0], sacc[2][tf][1]), fmaxf(sacc[2][tf][2], sacc[2][tf][3])), \
                fmaxf(fmaxf(sacc[3][tf][0], sacc[3][tf][1]), fmaxf(sacc[3][tf][2], sacc[3][tf][3])))); \
      mm = fmaxf(mm, __shfl_xor(mm, 16, 64));                                     \
      mm = fmaxf(mm, __shfl_xor(mm, 32, 64));                                     \
      mx[tf] = mm;                                                                \
    }                                                                             \
    int need = (mx[0] > mrow[0] + 8.f) | (mx[1] > mrow[1] + 8.f);                 \
    if (__any(need)) {                                                            \
      float mn0 = fmaxf(mrow[0], mx[0]), mn1 = fmaxf(mrow[1], mx[1]);             \
      float co[2] = {fexp2(mrow[0] - mn0), fexp2(mrow[1] - mn1)};                 \
      mrow[0] = mn0; mrow[1] = mn1;                                               \
      _Pragma("unroll")                                                           \
      for (int mf = 0; mf < 2; mf++)                                              \
        _Pragma("unroll")                                                         \
        for (int r = 0; r < 4; r++) {                                             \
          float cc = __shfl(co[mf], lg * 4 + r, 16);                              \
          oext[mf][r] *= cc;                                                      \
          _Pragma("unroll")                                                       \
          for (int nf = 0; nf < 4; nf++) oacc[mf][nf][r] *= cc;                   \
        }                                                                         \
    }                                                                             \
    _Pragma("unroll")                                                             \
    for (int tf = 0; tf < 2; tf++)                                                \
      _Pragma("unroll")                                                           \
      for (int lf = 0; lf < 4; lf++) {                                            \
        bf16x4 p4;                                                                \
        _Pragma("unroll")                                                         \
        for (int r = 0; r < 4; r++)                                               \
          p4[r] = (bf16)fexp2(sacc[lf][tf][r] - mrow[tf]);                        \
        int byte = (tf * 16 + lr) * 128 + (lf * 16 + lg * 4) * 2;                 \
        byte ^= (lr & 7) << 4;                                                    \
        *(bf16x4*)((char*)myP + byte) = p4;                                       \
      }                                                                           \
    bf16x8 pa[2][2];                                                              \
    _Pragma("unroll")                                                             \
    for (int mf = 0; mf < 2; mf++)                                                \
      _Pragma("unroll")                                                           \
      for (int ks = 0; ks < 2; ks++) {                                            \
        int byte = (mf * 16 + lr) * 128 + (lg * 8 + ks * 32) * 2;                 \
        byte ^= (lr & 7) << 4;                                                    \
        pa[mf][ks] = *(const bf16x8*)((const char*)myP + byte);                   \
      }                                                                           \
    __builtin_amdgcn_s_setprio(1);                                                \
    _Pragma("unroll")                                                             \
    for (int mf = 0; mf < 2; mf++) {                                              \
      _Pragma("unroll")                                                           \
      for (int nf = 0; nf < 4; nf++)                                              \
        _Pragma("unroll")                                                         \
        for (int ks = 0; ks < 2; ks++)                                            \
          oacc[mf][nf] = mfma16(pa[mf][ks], vf[nf][ks], oacc[mf][nf]);            \
      _Pragma("unroll")                                                           \
      for (int ks = 0; ks < 2; ks++)                                              \
        oext[mf] = mfma16(pa[mf][ks], ones8, oext[mf]);                           \
    }                                                                             \
    __builtin_amdgcn_s_setprio(0);                                                \
  }

__global__ __launch_bounds__(256, 2) void k_attn(
    const bf16* __restrict__ Qb, const bf16* __restrict__ Kf, const bf16* __restrict__ Vf,
    bf16* __restrict__ AO) {
  int bid = blockIdx.x;
  int sw = (bid & 7) * 64 + (bid >> 3);   // bijective XCD swizzle (512 = 8*64)
  int qt = sw & 15, h = (sw >> 4) & 7, b = sw >> 7;

  int wid = threadIdx.x >> 6, lane = threadIdx.x & 63;
  int lr = lane & 15, lg = lane >> 4;
  int t0 = qt * 128 + wid * 32;

  __shared__ bf16 Plds[4][32 * 64];
  bf16* myP = &Plds[wid][0];

  // Q fragments (B-operand of swapped QK^T): t = t0+tf*16+lr, k = lg*8+ks*32+j
  const bf16* Qbase = Qb + ((size_t)(b * 2048 + t0 + lr)) * AD + h * HD + lg * 8;
  bf16x8 qf[2][2];
  #pragma unroll
  for (int tf = 0; tf < 2; tf++)
    #pragma unroll
    for (int ks = 0; ks < 2; ks++)
      qf[tf][ks] = *(const bf16x8*)(Qbase + (size_t)tf * 16 * AD + ks * 32);

  bf16x8 ones8;
  #pragma unroll
  for (int j = 0; j < 8; j++) ones8[j] = (bf16)1.0f;

  float mrow[2] = {-1e30f, -1e30f};
  f32x4 oacc[2][4] = {};
  f32x4 oext[2] = {};

  const bf16* KfB = Kf + ((size_t)((b * NH + h) * 32)) * 4096 + lane * 8;
  const bf16* VfB = Vf + ((size_t)((b * NH + h) * 32)) * 4096 + lane * 8;

  // prologue: K frags for tile 0
  bf16x8 kfA[4][2], kfB_[4][2], vf[4][2];
  #pragma unroll
  for (int lf = 0; lf < 4; lf++)
    #pragma unroll
    for (int ks = 0; ks < 2; ks++)
      kfA[lf][ks] = *(const bf16x8*)(KfB + (lf * 2 + ks) * 512);

  #pragma unroll 1
  for (int t2 = 0; t2 < 32; t2 += 2) {
    ATT_BODY(t2,     kfA,  kfB_)
    ATT_BODY(t2 + 1, kfB_, kfA)
  }

  // epilogue: normalize, store AO (B,T,AD) bf16
  #pragma unroll
  for (int mf = 0; mf < 2; mf++)
    #pragma unroll
    for (int r = 0; r < 4; r++) {
      float inv = 1.0f / fmaxf(oext[mf][r], 1e-35f);
      int t = t0 + mf * 16 + lg * 4 + r;
      #pragma unroll
      for (int nf = 0; nf < 4; nf++)
        AO[((size_t)b * 2048 + t) * AD + h * HD + nf * 16 + lr] =
            (bf16)(oacc[mf][nf][r] * inv);
    }
}

// ---------------------------------------------------------------- output projection, transposed store
#define OUT_BODY(K0, AC, BC, AN, BN)                                              \
  {                                                                               \
    int _kn = ((K0) + 32) & 511;                                                  \
    int _kb = _kn >> 5;                                                           \
    _Pragma("unroll")                                                             \
    for (int mf = 0; mf < 2; mf++) AN[mf] = *(const bf16x8*)(Abase + mf * 8192 + _kb * 512); \
    _Pragma("unroll")                                                             \
    for (int nf = 0; nf < 4; nf++) BN[nf] = *(const bf16x8*)(Bbase + (size_t)nf * 16 * 512 + _kn); \
    __builtin_amdgcn_sched_barrier(0);                                            \
    _Pragma("unroll")                                                             \
    for (int mf = 0; mf < 2; mf++)                                                \
      _Pragma("unroll")                                                           \
      for (int nf = 0; nf < 4; nf++)                                              \
        acc[mf][nf] = mfma16(AC[mf], BC[nf], acc[mf][nf]);                        \
  }

__global__ __launch_bounds__(256, 2) void k_out(
    const bf16* __restrict__ AO, const bf16* __restrict__ Wp,
    const float* __restrict__ bo, const float* __restrict__ xm,
    float* __restrict__ out) {
  int n0 = blockIdx.x * 128, m0 = blockIdx.y * 64;
  int wid = threadIdx.x >> 6, lane = threadIdx.x & 63;
  int lr = lane & 15, lg = lane >> 4;
  int mw = m0 + (wid >> 1) * 32, nw = n0 + (wid & 1) * 64;

  const bf16* Abase = Wp + 3 * 262144 + (size_t)(mw >> 4) * 8192 + lane * 8;
  const bf16* Bbase = AO + ((size_t)(nw + lr)) * 512 + lg * 8;

  f32x4 acc[2][4] = {};
  bf16x8 afA[2], afB[2], bvA[4], bvB[4];
  #pragma unroll
  for (int mf = 0; mf < 2; mf++) afA[mf] = *(const bf16x8*)(Abase + mf * 8192);
  #pragma unroll
  for (int nf = 0; nf < 4; nf++) bvA[nf] = *(const bf16x8*)(Bbase + (size_t)nf * 16 * 512);

  for (int k0 = 0; k0 < 512; k0 += 64) {
    OUT_BODY(k0,      afA, bvA, afB, bvB)
    OUT_BODY(k0 + 32, afB, bvB, afA, bvA)
  }

  float bov[2][4];
  #pragma unroll
  for (int mf = 0; mf < 2; mf++)
    #pragma unroll
    for (int r = 0; r < 4; r++) bov[mf][r] = bo[mw + mf * 16 + lg * 4 + r];

  #pragma unroll
  for (int nf = 0; nf < 4; nf++) {
    int tg = nw + nf * 16 + lr;
    int b = tg >> 11, t = tg & 2047;
    float xmv = xm[b * 2048 + t];
    #pragma unroll
    for (int mf = 0; mf < 2; mf++)
      #pragma unroll
      for (int r = 0; r < 4; r++) {
        int d = mw + mf * 16 + lg * 4 + r;
        out[((size_t)b * DM + d) * TT + t] = (acc[mf][nf][r] + bov[mf][r]) * xmv;
      }
  }
}

// ---------------------------------------------------------------- launch
extern "C" void kernel_launch(void* const* d_in, const int* in_sizes, int n_in,
                              void* d_out, int out_size, void* d_ws, size_t ws_size,
                              hipStream_t stream) {
  const float* x     = (const float*)d_in[0];
  const float* ctx   = (const float*)d_in[1];
  const float* xmask = (const float*)d_in[2];
  const float* cmask = (const float*)d_in[3];
  const float* Wq = (const float*)d_in[4];
  const float* bq = (const float*)d_in[5];
  const float* Wk = (const float*)d_in[6];
  const float* bk = (const float*)d_in[7];
  const float* Wv = (const float*)d_in[8];
  const float* bv = (const float*)d_in[9];
  const float* Wo = (const float*)d_in[10];
  const float* bo = (const float*)d_in[11];
  float* out = (float*)d_out;

  char* w = (char*)d_ws;
  // ws layout: xp@0 (->AO), cp@8M (->Vf), Qb@16M, Kb@24M, Vb@32M (->Kf),
  //            Wp@40M (frag-pack x4), tab@42M..46M
  bf16* xp   = (bf16*)(w + 0);
  bf16* cp   = (bf16*)(w + 8388608);
  bf16* Qb   = (bf16*)(w + 16777216);
  bf16* Kb   = (bf16*)(w + 25165824);
  bf16* Vb   = (bf16*)(w + 33554432);
  bf16* Wp   = (bf16*)(w + 41943040);
  float2* tab = (float2*)(w + 44040192);
  bf16* AO = xp;    // xp dead after k_qkv
  bf16* Vf = cp;    // cp dead after k_qkv
  bf16* Kf = Vb;    // Vb dead after k_tr_vf

  k_tab<<<dim3(16, 4, 2), 256, 0, stream>>>(xmask, cmask, tab);
  k_packA<<<dim3(8, 8),   256, 0, stream>>>(Wq, Wp);
  k_packA<<<dim3(8, 8),   256, 0, stream>>>(Wk, Wp + 262144);
  k_packA<<<dim3(8, 8),   256, 0, stream>>>(Wv, Wp + 2 * 262144);
  k_packA<<<dim3(8, 8),   256, 0, stream>>>(Wo, Wp + 3 * 262144);
  k_packA<<<dim3(128, 8), 256, 0, stream>>>(ctx, cp);
  k_tr_x<<<dim3(TT / 64, DM / 64, BB), 256, 0, stream>>>(x, xp);
  k_qkv<<<dim3(4, 64, 3), 256, 0, stream>>>(xp, cp, Wp, bq, bk, bv, tab, Qb, Kb, Vb);
  k_tr_vf<<<dim3(32, NH, BB), 256, 0, stream>>>(Vb, Vf);
  k_repack_k<<<dim3(32, NH, BB), 256, 0, stream>>>(Kb, Kf);
  k_attn<<<512, 256, 0, stream>>>(Qb, Kf, Vf, AO);
  k_out<<<dim3(64, 8), 256, 0, stream>>>(AO, Wp, bo, xmask, out);
}